// Round 2
// baseline (6552.038 us; speedup 1.0000x reference)
//
#include <hip/hip_runtime.h>
#include <hip/hip_fp16.h>

namespace {
constexpr int ICH = 8, IH = 128, IW = 128;
constexpr int CPG = 4, PH = 31;
constexpr float EPS = 1e-5f;

__global__ __launch_bounds__(256, 4) void fused_conv_gn_pool(
    const float* __restrict__ x, const float* __restrict__ cw,
    const float* __restrict__ cb, const float* __restrict__ gnw,
    const float* __restrict__ gnb, const float* __restrict__ sc,
    float* __restrict__ out) {
  __shared__ float strip[ICH][6][132];     // 25344 B, plain layout (no swizzle)
  __shared__ float wlds[CPG][96];          // 1536 B, 12-padded 9-tap sets
  __shared__ __half mm[CPG][PH][PH];       // 7688 B, selected pool extreme
  __shared__ float red[8];
  __shared__ float stats[2];

  const int bid = blockIdx.x;
  const int xcd = bid & 7;                 // all 16 groups of an image on one XCD
  const int kb = bid >> 3;
  const int n = xcd * 16 + (kb >> 4);
  const int g = kb & 15;
  const int t = threadIdx.x;

  const int c  = t >> 6;                   // wave id = local channel 0..3
  const int u  = t & 63;
  const int r0 = u >> 5;                   // rows 2r0, 2r0+1 of each window
  const int j  = u & 31;                   // cols 4j..4j+3
  const int gc = g * CPG + c;

  // stage weights: wlds[c][ic*12 + k] = w[ic][k], k<9
  for (int idx = t; idx < CPG * 72; idx += 256) {
    int cc = idx / 72, i = idx - cc * 72;
    wlds[cc][(i / 9) * 12 + (i % 9)] = cw[(g * CPG + cc) * 72 + i];
  }
  const float bias = cb[gc];
  const bool sel = (gnw[gc] * sc[gc]) >= 0.f;  // slope sign known pre-stats

  const float* xn = x + (size_t)n * ICH * IH * IW;
  const int ch = t & 31;
  const int q = t >> 5;

  // ---- prologue: stage rows 0..5 ----
  float4 pre[6];
#pragma unroll
  for (int kk = 0; kk < 6; ++kk) {
    int idx = q + kk * 8;
    int ic = idx / 6, row = idx - ic * 6;
    pre[kk] = *reinterpret_cast<const float4*>(xn + (size_t)(ic * IH + row) * IW + ch * 4);
  }
#pragma unroll
  for (int kk = 0; kk < 6; ++kk) {
    int idx = q + kk * 8;
    int ic = idx / 6, row = idx - ic * 6;
    *reinterpret_cast<float4*>(&strip[ic][row][ch * 4]) = pre[kk];
  }
  float s1 = 0.f, s2 = 0.f;
  __syncthreads();

  for (int wh = 0; wh < PH; ++wh) {
    // ---- issue prefetch for next stage (overlaps with compute below) ----
    float4 nxt[6];
    if (wh < PH - 1) {
      const int br = 4 * (wh + 1);
#pragma unroll
      for (int kk = 0; kk < 6; ++kk) {
        int idx = q + kk * 8;
        int ic = idx / 6, row = idx - ic * 6;
        nxt[kk] = *reinterpret_cast<const float4*>(xn + (size_t)(ic * IH + br + row) * IW + ch * 4);
      }
    } else {  // tail: rows 124..127
#pragma unroll
      for (int kk = 0; kk < 4; ++kk) {
        int idx = q + kk * 8;
        int ic = idx >> 2, row = idx & 3;
        nxt[kk] = *reinterpret_cast<const float4*>(xn + (size_t)(ic * IH + 124 + row) * IW + ch * 4);
      }
    }
    // ---- conv: 2 adjacent rows (2r0, 2r0+1) x 4 cols ----
    float a[2][4] = {{0.f, 0.f, 0.f, 0.f}, {0.f, 0.f, 0.f, 0.f}};
#pragma unroll
    for (int ic = 0; ic < ICH; ++ic) {
      float4 wA = *reinterpret_cast<const float4*>(&wlds[c][ic * 12]);
      float4 wB = *reinterpret_cast<const float4*>(&wlds[c][ic * 12 + 4]);
      float w8 = wlds[c][ic * 12 + 8];
      const float w[9] = {wA.x, wA.y, wA.z, wA.w, wB.x, wB.y, wB.z, wB.w, w8};
      float in4[4][6];
#pragma unroll
      for (int rr = 0; rr < 4; ++rr) {
        const float* rp = &strip[ic][2 * r0 + rr][4 * j];
        float4 v4 = *reinterpret_cast<const float4*>(rp);
        float2 v2 = *reinterpret_cast<const float2*>(rp + 4);
        in4[rr][0] = v4.x; in4[rr][1] = v4.y; in4[rr][2] = v4.z; in4[rr][3] = v4.w;
        in4[rr][4] = v2.x; in4[rr][5] = v2.y;
      }
#pragma unroll
      for (int tk = 0; tk < 2; ++tk)
#pragma unroll
        for (int dh = 0; dh < 3; ++dh)
#pragma unroll
          for (int dw = 0; dw < 3; ++dw) {
            const float wv = w[dh * 3 + dw];
            a[tk][0] = fmaf(in4[tk + dh][dw + 0], wv, a[tk][0]);
            a[tk][1] = fmaf(in4[tk + dh][dw + 1], wv, a[tk][1]);
            a[tk][2] = fmaf(in4[tk + dh][dw + 2], wv, a[tk][2]);
            a[tk][3] = fmaf(in4[tk + dh][dw + 3], wv, a[tk][3]);
          }
    }
    float mx = -3.4e38f, mn = 3.4e38f;
#pragma unroll
    for (int tk = 0; tk < 2; ++tk) {
      a[tk][0] += bias; a[tk][1] += bias; a[tk][2] += bias; a[tk][3] += bias;
      mx = fmaxf(mx, fmaxf(fmaxf(a[tk][0], a[tk][1]), fmaxf(a[tk][2], a[tk][3])));
      mn = fminf(mn, fminf(fminf(a[tk][0], a[tk][1]), fminf(a[tk][2], a[tk][3])));
      if (j < 31) {
        s1 += a[tk][0] + a[tk][1] + a[tk][2] + a[tk][3];
        s2 += a[tk][0] * a[tk][0] + a[tk][1] * a[tk][1] + a[tk][2] * a[tk][2] + a[tk][3] * a[tk][3];
      } else {
        s1 += a[tk][0] + a[tk][1];
        s2 += a[tk][0] * a[tk][0] + a[tk][1] * a[tk][1];
      }
    }
    // combine r0 halves -> full 4x4 window extreme; write selected as f16
    float e = sel ? mx : mn;
    float o = __shfl_xor(e, 32, 64);
    e = sel ? fmaxf(e, o) : fminf(e, o);
    if (u < 31) mm[c][wh][u] = __float2half(e);
    __syncthreads();
    // ---- write staged rows (prefetch has landed under the compute) ----
    if (wh < PH - 1) {
#pragma unroll
      for (int kk = 0; kk < 6; ++kk) {
        int idx = q + kk * 8;
        int ic = idx / 6, row = idx - ic * 6;
        *reinterpret_cast<float4*>(&strip[ic][row][ch * 4]) = nxt[kk];
      }
    } else {
#pragma unroll
      for (int kk = 0; kk < 4; ++kk) {
        int idx = q + kk * 8;
        int ic = idx >> 2, row = idx & 3;
        *reinterpret_cast<float4*>(&strip[ic][row][ch * 4]) = nxt[kk];
      }
    }
    __syncthreads();
  }

  // ---- tail rows 124,125: stats only (each thread one row r0) ----
  {
    float a0 = 0.f, a1 = 0.f, a2 = 0.f, a3 = 0.f;
#pragma unroll
    for (int ic = 0; ic < ICH; ++ic) {
      float4 wA = *reinterpret_cast<const float4*>(&wlds[c][ic * 12]);
      float4 wB = *reinterpret_cast<const float4*>(&wlds[c][ic * 12 + 4]);
      float w8 = wlds[c][ic * 12 + 8];
      const float w[9] = {wA.x, wA.y, wA.z, wA.w, wB.x, wB.y, wB.z, wB.w, w8};
      float in3[3][6];
#pragma unroll
      for (int rr = 0; rr < 3; ++rr) {
        const float* rp = &strip[ic][r0 + rr][4 * j];
        float4 v4 = *reinterpret_cast<const float4*>(rp);
        float2 v2 = *reinterpret_cast<const float2*>(rp + 4);
        in3[rr][0] = v4.x; in3[rr][1] = v4.y; in3[rr][2] = v4.z; in3[rr][3] = v4.w;
        in3[rr][4] = v2.x; in3[rr][5] = v2.y;
      }
#pragma unroll
      for (int dh = 0; dh < 3; ++dh)
#pragma unroll
        for (int dw = 0; dw < 3; ++dw) {
          const float wv = w[dh * 3 + dw];
          a0 = fmaf(in3[dh][dw + 0], wv, a0);
          a1 = fmaf(in3[dh][dw + 1], wv, a1);
          a2 = fmaf(in3[dh][dw + 2], wv, a2);
          a3 = fmaf(in3[dh][dw + 3], wv, a3);
        }
    }
    a0 += bias; a1 += bias; a2 += bias; a3 += bias;
    if (j < 31) {
      s1 += a0 + a1 + a2 + a3;
      s2 += a0 * a0 + a1 * a1 + a2 * a2 + a3 * a3;
    } else {
      s1 += a0 + a1;
      s2 += a0 * a0 + a1 * a1;
    }
  }

  // ---- block reduction ----
#pragma unroll
  for (int off = 32; off > 0; off >>= 1) {
    s1 += __shfl_down(s1, off, 64);
    s2 += __shfl_down(s2, off, 64);
  }
  if (u == 0) { red[c * 2] = s1; red[c * 2 + 1] = s2; }
  __syncthreads();
  if (t == 0) {
    float S1 = red[0] + red[2] + red[4] + red[6];
    float S2 = red[1] + red[3] + red[5] + red[7];
    constexpr float invN = 1.f / (CPG * 126.f * 126.f);
    float mean = S1 * invN;
    float var = S2 * invN - mean * mean;
    stats[0] = mean;
    stats[1] = rsqrtf(var + EPS);
  }
  __syncthreads();
  const float mean = stats[0], inv = stats[1];

  // ---- epilogue ----
  float* outp = out + ((size_t)n * 64 + g * CPG) * (PH * PH);
  for (int kk = 0; kk < 16; ++kk) {
    int idx = t + kk * 256;
    if (idx < CPG * PH * PH) {
      int cc = idx / (PH * PH);
      int rem = idx - cc * (PH * PH);
      float e = __half2float(mm[cc][rem / PH][rem - (rem / PH) * PH]);
      int gcc = g * CPG + cc;
      float gw = gnw[gcc];
      float A = gw * inv * sc[gcc];
      float B = (gnb[gcc] - mean * inv * gw) * sc[gcc];
      float v = A * e + B;
      v = fminf(fmaxf(v, 0.f), 1.f);
      outp[cc * (PH * PH) + rem] = v;
    }
  }
}
}  // namespace

extern "C" void kernel_launch(void* const* d_in, const int* in_sizes, int n_in,
                              void* d_out, int out_size, void* d_ws, size_t ws_size,
                              hipStream_t stream) {
  const float* x   = (const float*)d_in[0];
  const float* cw  = (const float*)d_in[1];
  const float* cb  = (const float*)d_in[2];
  const float* gnw = (const float*)d_in[3];
  const float* gnb = (const float*)d_in[4];
  const float* sc  = (const float*)d_in[5];
  float* out = (float*)d_out;
  hipLaunchKernelGGL(fused_conv_gn_pool, dim3(2048), dim3(256), 0, stream,
                     x, cw, cb, gnw, gnb, sc, out);
}

// Round 3
// 1274.561 us; speedup vs baseline: 5.1406x; 5.1406x over previous
//
#include <hip/hip_runtime.h>
#include <hip/hip_fp16.h>

namespace {
constexpr int ICH = 8, IH = 128, IW = 128;
constexpr int CPG = 4, PH = 31;
constexpr float EPS = 1e-5f;
constexpr float MPX = 126.f * 126.f;

__device__ __forceinline__ void gll16(const void* g, void* l) {
  __builtin_amdgcn_global_load_lds((const __attribute__((address_space(1))) void*)g,
                                   (__attribute__((address_space(3))) void*)l, 16, 0, 0);
}

// T2 completes this row; T1 gets mid tap-row; T0 gets top tap-row (init'd 0).
#define CROW(RR, T2, T1, T0)                                                   \
  {                                                                            \
    _Pragma("unroll") for (int i4 = 0; i4 < 4; ++i4) {                         \
      const float* rp = bp + ((4 * p + i4) * 4 + (RR)) * IW + 4 * j;           \
      float4 v4 = *reinterpret_cast<const float4*>(rp);                        \
      float2 v2 = (j < 31) ? *reinterpret_cast<const float2*>(rp + 4)          \
                           : make_float2(0.f, 0.f);                            \
      float in[6] = {v4.x, v4.y, v4.z, v4.w, v2.x, v2.y};                      \
      _Pragma("unroll") for (int dw = 0; dw < 3; ++dw) {                       \
        const float w0 = wf[i4 * 9 + dw];                                      \
        const float w1 = wf[i4 * 9 + 3 + dw];                                  \
        const float w2 = wf[i4 * 9 + 6 + dw];                                  \
        _Pragma("unroll") for (int q = 0; q < 4; ++q) {                        \
          T2[q] = fmaf(in[q + dw], w2, T2[q]);                                 \
          T1[q] = fmaf(in[q + dw], w1, T1[q]);                                 \
          T0[q] = fmaf(in[q + dw], w0, T0[q]);                                 \
        }                                                                      \
      }                                                                        \
    }                                                                          \
  }

// Combine ic-halves, accumulate stats (masked), emit flipped row-extreme.
#define FIN(T, DOSTATS, RE)                                                    \
  {                                                                            \
    float f0 = T[0] + __shfl_xor(T[0], 32, 64);                                \
    float f1 = T[1] + __shfl_xor(T[1], 32, 64);                                \
    float f2 = T[2] + __shfl_xor(T[2], 32, 64);                                \
    float f3 = T[3] + __shfl_xor(T[3], 32, 64);                                \
    if (DOSTATS) {                                                             \
      s1 += f0 + f1 + m23 * (f2 + f3);                                         \
      float qa = fmaf(f0, f0, f1 * f1);                                        \
      float qb = fmaf(f2, f2, f3 * f3);                                        \
      s2 += qa + m23 * qb;                                                     \
    }                                                                          \
    RE = fmaxf(fmaxf(flip * f0, flip * f1), fmaxf(flip * f2, flip * f3));      \
  }

__global__ __launch_bounds__(256, 4) void fused_conv_gn_pool(
    const float* __restrict__ x, const float* __restrict__ cw,
    const float* __restrict__ cb, const float* __restrict__ gnw,
    const float* __restrict__ gnb, const float* __restrict__ sc,
    float* __restrict__ out) {
  __shared__ float buf[2][ICH][4][IW];   // 32768 B, linear (global_load_lds dest)
  __shared__ __half mm[CPG][PH][PH];     // 7688 B
  __shared__ float red[8];
  __shared__ float stats[2];

  const int bid = blockIdx.x;
  const int xcd = bid & 7;               // image's 16 groups share one XCD L2
  const int kb = bid >> 3;
  const int n = xcd * 16 + (kb >> 4);
  const int g = kb & 15;
  const int t = threadIdx.x;
  const int c = t >> 6;                  // wave = output channel within group
  const int u = t & 63;
  const int p = u >> 5;                  // ic-half: 0 -> ic 0..3, 1 -> ic 4..7
  const int j = u & 31;                  // output cols 4j..4j+3
  const int gc = g * CPG + c;

  float wf[36];                          // this lane's 4 ics x 9 taps
  {
    const float4* wp = reinterpret_cast<const float4*>(cw + gc * 72 + p * 36);
#pragma unroll
    for (int q = 0; q < 9; ++q) {
      float4 v = wp[q];
      wf[4 * q + 0] = v.x; wf[4 * q + 1] = v.y;
      wf[4 * q + 2] = v.z; wf[4 * q + 3] = v.w;
    }
  }
  const float flip = ((gnw[gc] * sc[gc]) >= 0.f) ? 1.f : -1.f;
  const float m23 = (j < 31) ? 1.f : 0.f;   // lane 31: only cols 124,125 valid

  const float* xn = x + (size_t)n * ICH * IH * IW;

  // Stage 4 input rows (all 8 ic) into buf[which]; 16 x 1KB wave-chunks, 4/wave.
  auto issue = [&](int br, int which) {
#pragma unroll
    for (int k = 0; k < 4; ++k) {
      const int m = c * 4 + k;
      const int ic = m >> 1;
      const int r2 = (m & 1) * 2;        // rows r2, r2+1 of the stage
      const float* gp = xn + (size_t)(ic * IH + br + r2) * IW + u * 4;
      gll16(gp, &buf[which][ic][r2][0]);
    }
  };

  issue(0, 0);

  float s1 = 0.f, s2 = 0.f, wprev = 0.f;
  float P2[4] = {0, 0, 0, 0}, P1[4] = {0, 0, 0, 0};

  for (int s = 0; s < 32; ++s) {
    __syncthreads();                      // drains exactly the 4 loads we need
    const int cur = s & 1;
    if (s < 31) issue(4 * (s + 1), cur ^ 1);
    const float* bp = &buf[cur][0][0][0];

    float N0[4] = {0, 0, 0, 0}, N1[4] = {0, 0, 0, 0};
    float N2[4] = {0, 0, 0, 0}, N3[4] = {0, 0, 0, 0};

    CROW(0, P2, P1, N0)                   // completes out row 4s-2
    CROW(1, P1, N0, N1)                   // completes out row 4s-1
    CROW(2, N0, N1, N2)                   // completes out row 4s
    CROW(3, N1, N2, N3)                   // completes out row 4s+1

    const bool v01 = (s > 0);
    float re0, re1, re2, re3;
    FIN(P2, v01, re0)
    FIN(P1, v01, re1)
    if (v01) {                            // finalize pool window s-1 (rows 4s-4..4s-1)
      float wfin = fmaxf(wprev, fmaxf(re0, re1));
      if (p == 0 && j < 31) mm[c][s - 1][j] = __float2half(flip * wfin);
    }
    FIN(N0, true, re2)
    FIN(N1, true, re3)
    wprev = fmaxf(re2, re3);

#pragma unroll
    for (int q = 0; q < 4; ++q) { P2[q] = N2[q]; P1[q] = N3[q]; }
  }

  // ---- block reduction (each value counted twice across ic-halves -> 0.5x) ----
#pragma unroll
  for (int off = 32; off > 0; off >>= 1) {
    s1 += __shfl_down(s1, off, 64);
    s2 += __shfl_down(s2, off, 64);
  }
  const float bc = cb[gc];
  if (u == 0) {
    float t1 = 0.5f * s1, t2 = 0.5f * s2;       // true raw per-channel sums
    red[c * 2] = t1 + MPX * bc;                 // add bias analytically
    red[c * 2 + 1] = t2 + 2.f * bc * t1 + MPX * bc * bc;
  }
  __syncthreads();
  if (t == 0) {
    float S1 = red[0] + red[2] + red[4] + red[6];
    float S2 = red[1] + red[3] + red[5] + red[7];
    constexpr float invN = 1.f / (CPG * 126.f * 126.f);
    float mean = S1 * invN;
    float var = S2 * invN - mean * mean;
    stats[0] = mean;
    stats[1] = rsqrtf(var + EPS);
  }
  __syncthreads();
  const float mean = stats[0], inv = stats[1];

  // ---- epilogue: affine(+bias fold) + clamp + store ----
  float* outp = out + ((size_t)n * 64 + g * CPG) * (PH * PH);
  for (int kk = 0; kk < 16; ++kk) {
    int idx = t + kk * 256;
    if (idx < CPG * PH * PH) {
      int cc = idx / (PH * PH);
      int rem = idx - cc * (PH * PH);
      float e = __half2float(mm[cc][rem / PH][rem % PH]);
      int gcc = g * CPG + cc;
      float gw = gnw[gcc];
      float A = gw * inv * sc[gcc];
      float B = (gnb[gcc] - mean * inv * gw) * sc[gcc] + A * cb[gcc];
      float v = fmaf(A, e, B);
      v = fminf(fmaxf(v, 0.f), 1.f);
      outp[cc * (PH * PH) + rem] = v;
    }
  }
}
}  // namespace

extern "C" void kernel_launch(void* const* d_in, const int* in_sizes, int n_in,
                              void* d_out, int out_size, void* d_ws, size_t ws_size,
                              hipStream_t stream) {
  const float* x   = (const float*)d_in[0];
  const float* cw  = (const float*)d_in[1];
  const float* cb  = (const float*)d_in[2];
  const float* gnw = (const float*)d_in[3];
  const float* gnb = (const float*)d_in[4];
  const float* sc  = (const float*)d_in[5];
  float* out = (float*)d_out;
  hipLaunchKernelGGL(fused_conv_gn_pool, dim3(2048), dim3(256), 0, stream,
                     x, cw, cb, gnw, gnb, sc, out);
}

// Round 4
// 630.177 us; speedup vs baseline: 10.3971x; 2.0225x over previous
//
#include <hip/hip_runtime.h>
#include <hip/hip_fp16.h>

namespace {
constexpr int ICH = 8, IH = 128, IW = 128;
constexpr int CPG = 4, PH = 31;
constexpr float EPS = 1e-5f;
constexpr float MPX = 126.f * 126.f;

__device__ __forceinline__ void gll16(const void* g, void* l) {
  __builtin_amdgcn_global_load_lds((const __attribute__((address_space(1))) void*)g,
                                   (__attribute__((address_space(3))) void*)l, 16, 0, 0);
}

// Process staged row RR: T2 += tap-row2 (completes), T1 += tap-row1, T0 += tap-row0.
#define ROW(RR, T2, T1, T0)                                                    \
  {                                                                            \
    _Pragma("unroll") for (int i4 = 0; i4 < 4; ++i4) {                         \
      const float* rp = bp + ((4 * p + i4) * 4 + (RR)) * IW + 4 * j;           \
      float4 v4 = *reinterpret_cast<const float4*>(rp);                        \
      float2 v2 = (j < 31) ? *reinterpret_cast<const float2*>(rp + 4)          \
                           : make_float2(0.f, 0.f);                            \
      float in[6] = {v4.x, v4.y, v4.z, v4.w, v2.x, v2.y};                      \
      _Pragma("unroll") for (int dw = 0; dw < 3; ++dw) {                       \
        const float w0 = wf[i4 * 9 + dw];                                      \
        const float w1 = wf[i4 * 9 + 3 + dw];                                  \
        const float w2 = wf[i4 * 9 + 6 + dw];                                  \
        _Pragma("unroll") for (int q = 0; q < 4; ++q) {                        \
          T2[q] = fmaf(in[q + dw], w2, T2[q]);                                 \
          T1[q] = fmaf(in[q + dw], w1, T1[q]);                                 \
          T0[q] = fmaf(in[q + dw], w0, T0[q]);                                 \
        }                                                                      \
      }                                                                        \
    }                                                                          \
  }

// Combine ic-halves, accumulate stats (masked col tail), emit flipped extreme.
#define FIN(T, DOSTATS, RE)                                                    \
  {                                                                            \
    float f0 = T[0] + __shfl_xor(T[0], 32, 64);                                \
    float f1 = T[1] + __shfl_xor(T[1], 32, 64);                                \
    float f2 = T[2] + __shfl_xor(T[2], 32, 64);                                \
    float f3 = T[3] + __shfl_xor(T[3], 32, 64);                                \
    if (DOSTATS) {                                                             \
      s1 += f0 + f1 + m23 * (f2 + f3);                                         \
      float qa = fmaf(f0, f0, f1 * f1);                                        \
      float qb = fmaf(f2, f2, f3 * f3);                                        \
      s2 += qa + m23 * qb;                                                     \
    }                                                                          \
    RE = fmaxf(fmaxf(flip * f0, flip * f1), fmaxf(flip * f2, flip * f3));      \
  }

#define ZERO(T) { T[0] = 0.f; T[1] = 0.f; T[2] = 0.f; T[3] = 0.f; }

// One 4-row stage. Completes output rows 4S-2, 4S-1, 4S, 4S+1 (names X,Y,Z,X).
#define STAGE(S, X, Y, Z, DOS01, DOWIN)                                        \
  {                                                                            \
    __syncthreads();                                                           \
    const int cur = (S) & 1;                                                   \
    if ((S) < 31) issue(4 * ((S) + 1), cur ^ 1);                               \
    const float* bp = &buf[cur][0][0][0];                                      \
    float re0, re1, re2, re3;                                                  \
    ROW(0, X, Y, Z) FIN(X, DOS01, re0) ZERO(X)                                 \
    ROW(1, Y, Z, X) FIN(Y, DOS01, re1) ZERO(Y)                                 \
    if (DOWIN) {                                                               \
      float wfin = fmaxf(wprev, fmaxf(re0, re1));                              \
      if (p == 0 && j < 31) mm[c][(S) - 1][j] = __float2half(flip * wfin);     \
    }                                                                          \
    ROW(2, Z, X, Y) FIN(Z, true, re2) ZERO(Z)                                  \
    ROW(3, X, Y, Z) FIN(X, true, re3) ZERO(X)                                  \
    wprev = fmaxf(re2, re3);                                                   \
  }

__global__ void __attribute__((amdgpu_flat_work_group_size(256, 256),
                               amdgpu_waves_per_eu(4, 4)))
fused_conv_gn_pool(
    const float* __restrict__ x, const float* __restrict__ cw,
    const float* __restrict__ cb, const float* __restrict__ gnw,
    const float* __restrict__ gnb, const float* __restrict__ sc,
    float* __restrict__ out) {
  __shared__ float buf[2][ICH][4][IW];   // 32768 B, linear (global_load_lds dest)
  __shared__ __half mm[CPG][PH][PH];     // 7688 B
  __shared__ float red[8];
  __shared__ float stats[2];

  const int bid = blockIdx.x;
  const int xcd = bid & 7;               // image's 16 groups share one XCD L2
  const int kb = bid >> 3;
  const int n = xcd * 16 + (kb >> 4);
  const int g = kb & 15;
  const int t = threadIdx.x;
  const int c = t >> 6;                  // wave = output channel within group
  const int u = t & 63;
  const int p = u >> 5;                  // ic-half: 0 -> ic 0..3, 1 -> ic 4..7
  const int j = u & 31;                  // output cols 4j..4j+3
  const int gc = g * CPG + c;

  float wf[36];                          // this lane's 4 ics x 9 taps
  {
    const float4* wp = reinterpret_cast<const float4*>(cw + gc * 72 + p * 36);
#pragma unroll
    for (int q = 0; q < 9; ++q) {
      float4 v = wp[q];
      wf[4 * q + 0] = v.x; wf[4 * q + 1] = v.y;
      wf[4 * q + 2] = v.z; wf[4 * q + 3] = v.w;
    }
  }
  const float flip = ((gnw[gc] * sc[gc]) >= 0.f) ? 1.f : -1.f;
  const float m23 = (j < 31) ? 1.f : 0.f;   // lane 31: only cols 124,125 valid

  const float* xn = x + (size_t)n * ICH * IH * IW;

  // Stage 4 input rows (all 8 ic) into buf[which]; 16 x 1KB wave-chunks, 4/wave.
  auto issue = [&](int br, int which) {
#pragma unroll
    for (int k = 0; k < 4; ++k) {
      const int m = c * 4 + k;
      const int ic = m >> 1;
      const int r2 = (m & 1) * 2;        // rows r2, r2+1 of the stage
      const float* gp = xn + (size_t)(ic * IH + br + r2) * IW + u * 4;
      gll16(gp, &buf[which][ic][r2][0]);
    }
  };

  issue(0, 0);

  float s1 = 0.f, s2 = 0.f, wprev = 0.f;
  float A0[4] = {0, 0, 0, 0}, A1[4] = {0, 0, 0, 0}, A2[4] = {0, 0, 0, 0};

  // Stage 0: completed rows -2,-1 are invalid (no stats, no window).
  STAGE(0, A0, A1, A2, false, false)
  // Stages 1..30 in 3-phase triplets (pending-name permutation has period 3).
  for (int s = 1; s <= 28; s += 3) {
    STAGE(s,     A1, A2, A0, true, true)
    STAGE(s + 1, A2, A0, A1, true, true)
    STAGE(s + 2, A0, A1, A2, true, true)
  }
  // Stage 31 (31 % 3 == 1 -> phase (A1,A2,A0)); finalizes window 30.
  STAGE(31, A1, A2, A0, true, true)

  // ---- block reduction (each value counted twice across ic-halves -> 0.5x) ----
#pragma unroll
  for (int off = 32; off > 0; off >>= 1) {
    s1 += __shfl_down(s1, off, 64);
    s2 += __shfl_down(s2, off, 64);
  }
  const float bc = cb[gc];
  if (u == 0) {
    float t1 = 0.5f * s1, t2 = 0.5f * s2;       // true raw per-channel sums
    red[c * 2] = t1 + MPX * bc;                 // add bias analytically
    red[c * 2 + 1] = t2 + 2.f * bc * t1 + MPX * bc * bc;
  }
  __syncthreads();
  if (t == 0) {
    float S1 = red[0] + red[2] + red[4] + red[6];
    float S2 = red[1] + red[3] + red[5] + red[7];
    constexpr float invN = 1.f / (CPG * 126.f * 126.f);
    float mean = S1 * invN;
    float var = S2 * invN - mean * mean;
    stats[0] = mean;
    stats[1] = rsqrtf(var + EPS);
  }
  __syncthreads();
  const float mean = stats[0], inv = stats[1];

  // ---- epilogue: affine(+bias fold) + clamp + store ----
  float* outp = out + ((size_t)n * 64 + g * CPG) * (PH * PH);
  for (int kk = 0; kk < 16; ++kk) {
    int idx = t + kk * 256;
    if (idx < CPG * PH * PH) {
      int cc = idx / (PH * PH);
      int rem = idx - cc * (PH * PH);
      float e = __half2float(mm[cc][rem / PH][rem % PH]);
      int gcc = g * CPG + cc;
      float gw = gnw[gcc];
      float A = gw * inv * sc[gcc];
      float B = (gnb[gcc] - mean * inv * gw) * sc[gcc] + A * cb[gcc];
      float v = fmaf(A, e, B);
      v = fminf(fmaxf(v, 0.f), 1.f);
      outp[cc * (PH * PH) + rem] = v;
    }
  }
}
}  // namespace

extern "C" void kernel_launch(void* const* d_in, const int* in_sizes, int n_in,
                              void* d_out, int out_size, void* d_ws, size_t ws_size,
                              hipStream_t stream) {
  const float* x   = (const float*)d_in[0];
  const float* cw  = (const float*)d_in[1];
  const float* cb  = (const float*)d_in[2];
  const float* gnw = (const float*)d_in[3];
  const float* gnb = (const float*)d_in[4];
  const float* sc  = (const float*)d_in[5];
  float* out = (float*)d_out;
  hipLaunchKernelGGL(fused_conv_gn_pool, dim3(2048), dim3(256), 0, stream,
                     x, cw, cb, gnw, gnb, sc, out);
}